// Round 17
// baseline (1022.074 us; speedup 1.0000x reference)
//
#include <hip/hip_runtime.h>
#include <hip/hip_bf16.h>
#include <math.h>

#define ALPHA 0.1f
#define K_ITERS 10
#define CHUNK 4096
#define PER_TH 16

typedef __attribute__((ext_vector_type(8))) short short8;
typedef __attribute__((ext_vector_type(4))) float floatx4;
typedef const __attribute__((address_space(1))) unsigned int gu32;
typedef __attribute__((address_space(3))) unsigned int lu32;

static __device__ __forceinline__ float bf2f(unsigned short u) {
    union { unsigned int i; float f; } v;
    v.i = ((unsigned int)u) << 16;
    return v.f;
}
static __device__ __forceinline__ unsigned short f2bf(float f) {
    union { float f; unsigned int i; } v;
    v.f = f;
    unsigned int r = v.i + 0x7FFF + ((v.i >> 16) & 1);   // round-nearest-even
    return (unsigned short)(r >> 16);
}

// ---------------- CSR build (no N-wide random atomics anywhere) ----------------

__global__ __launch_bounds__(256) void k_bcount(const int* __restrict__ ei, int E,
                                                int shift, int* __restrict__ bcnt) {
    __shared__ int h[256];
    h[threadIdx.x] = 0;
    __syncthreads();
    int stride = gridDim.x * blockDim.x;
    for (int e = blockIdx.x * blockDim.x + threadIdx.x; e < E; e += stride)
        atomicAdd(&h[ei[E + e] >> shift], 1);
    __syncthreads();
    if (h[threadIdx.x]) atomicAdd(&bcnt[threadIdx.x], h[threadIdx.x]);
}

__global__ __launch_bounds__(256) void k_boff(const int* __restrict__ bcnt,
                                              int* __restrict__ boff) {
    __shared__ int sc[256];
    int t = threadIdx.x;
    sc[t] = bcnt[t];
    __syncthreads();
    for (int o = 1; o < 256; o <<= 1) {
        int w = (t >= o) ? sc[t - o] : 0;
        __syncthreads();
        sc[t] += w;
        __syncthreads();
    }
    boff[t] = t ? sc[t - 1] : 0;
    if (t == 255) boff[256] = sc[255];   // == E
}

__global__ __launch_bounds__(256) void k_bucket2(const int* __restrict__ ei, int E,
                                                 const int* __restrict__ boff,
                                                 int* __restrict__ gcur,
                                                 int2* __restrict__ grouped,
                                                 int shift, int NB) {
    __shared__ int hist[256];
    __shared__ int sc[256];
    __shared__ int cursor[256];
    __shared__ int gdst[256];
    __shared__ int2 stage[CHUNK];
    int t = threadIdx.x;
    long e0 = (long)blockIdx.x * CHUNK;
    int total = (int)min((long)CHUNK, (long)E - e0);

    int sarr[PER_TH], darr[PER_TH];
    #pragma unroll
    for (int i = 0; i < PER_TH; ++i) {
        long e = e0 + t + i * 256;
        if (e < E) { sarr[i] = ei[e]; darr[i] = ei[E + e]; }
        else { sarr[i] = 0; darr[i] = -1; }
    }
    hist[t] = 0;
    __syncthreads();
    #pragma unroll
    for (int i = 0; i < PER_TH; ++i)
        if (darr[i] >= 0) atomicAdd(&hist[darr[i] >> shift], 1);
    __syncthreads();
    sc[t] = hist[t];
    __syncthreads();
    for (int o = 1; o < 256; o <<= 1) {
        int w = (t >= o) ? sc[t - o] : 0;
        __syncthreads();
        sc[t] += w;
        __syncthreads();
    }
    cursor[t] = sc[t] - hist[t];
    __syncthreads();
    #pragma unroll
    for (int i = 0; i < PER_TH; ++i)
        if (darr[i] >= 0) {
            int b = darr[i] >> shift;
            int pos = atomicAdd(&cursor[b], 1);
            stage[pos] = make_int2(sarr[i], darr[i]);
        }
    if (t < NB && hist[t] > 0)
        gdst[t] = boff[t] + atomicAdd(&gcur[t], hist[t]);
    __syncthreads();
    for (int i = t; i < total; i += 256) {
        int2 ent = stage[i];
        int b = ent.y >> shift;
        int r = i - (sc[b] - hist[b]);
        grouped[gdst[b] + r] = ent;
    }
}

__global__ __launch_bounds__(256) void k_rowcnt(const int2* __restrict__ grouped,
                                                const int* __restrict__ boff,
                                                int* __restrict__ cnt,
                                                float* __restrict__ dinv,
                                                int shift, int N) {
    __shared__ int lcnt[1024];
    int t = threadIdx.x;
    int rows = 1 << shift;
    int rlo = blockIdx.x << shift;
    int rhi = min(rlo + rows, N);
    for (int i = t; i < rows; i += 256) lcnt[i] = 0;
    __syncthreads();
    int base = boff[blockIdx.x], end = boff[blockIdx.x + 1];
    for (int i = base + t; i < end; i += 256)
        atomicAdd(&lcnt[grouped[i].y - rlo], 1);
    __syncthreads();
    for (int i = rlo + t; i < rhi; i += 256) {
        int c = lcnt[i - rlo];
        cnt[i] = c;
        dinv[i] = rsqrtf((float)(c + 1));   // +1 self loop
    }
}

// ---- parallel exclusive scan of cnt -> row_ptr ----

__global__ __launch_bounds__(256) void k_scan_part(const int* __restrict__ cnt,
                                                   int* __restrict__ partial, int N) {
    __shared__ int red[256];
    int t = threadIdx.x;
    int base = blockIdx.x * 1024 + t * 4;
    int s = 0;
    #pragma unroll
    for (int u = 0; u < 4; ++u) { int i = base + u; if (i < N) s += cnt[i]; }
    red[t] = s;
    __syncthreads();
    for (int o = 128; o; o >>= 1) {
        if (t < o) red[t] += red[t + o];
        __syncthreads();
    }
    if (t == 0) partial[blockIdx.x] = red[0];
}

__global__ __launch_bounds__(128) void k_scan_off(const int* __restrict__ partial,
                                                  int* __restrict__ blkoff,
                                                  int* __restrict__ row_ptr_last,
                                                  int nblk) {
    __shared__ int sc[128];
    int t = threadIdx.x;
    sc[t] = (t < nblk) ? partial[t] : 0;
    __syncthreads();
    for (int o = 1; o < 128; o <<= 1) {
        int w = (t >= o) ? sc[t - o] : 0;
        __syncthreads();
        sc[t] += w;
        __syncthreads();
    }
    if (t < nblk) blkoff[t] = t ? sc[t - 1] : 0;
    if (t == 127) *row_ptr_last = sc[127];
}

__global__ __launch_bounds__(256) void k_scan_write(const int* __restrict__ cnt,
                                                    const int* __restrict__ blkoff,
                                                    int* __restrict__ row_ptr, int N) {
    __shared__ int sc[256];
    int t = threadIdx.x;
    int base = blockIdx.x * 1024 + t * 4;
    int c[4];
    int s = 0;
    #pragma unroll
    for (int u = 0; u < 4; ++u) {
        int i = base + u;
        c[u] = (i < N) ? cnt[i] : 0;
        s += c[u];
    }
    sc[t] = s;
    __syncthreads();
    for (int o = 1; o < 256; o <<= 1) {
        int w = (t >= o) ? sc[t - o] : 0;
        __syncthreads();
        sc[t] += w;
        __syncthreads();
    }
    int run = blkoff[blockIdx.x] + (t ? sc[t - 1] : 0);
    #pragma unroll
    for (int u = 0; u < 4; ++u) {
        int i = base + u;
        if (i < N) { row_ptr[i] = run; run += c[u]; }
    }
}

__global__ __launch_bounds__(256) void k_fill2(const int2* __restrict__ grouped,
                                               const int* __restrict__ row_ptr,
                                               const float* __restrict__ dinv,
                                               int2* __restrict__ packed,
                                               int shift, int N) {
    __shared__ int lcnt[1024];
    int t = threadIdx.x;
    int rows = 1 << shift;
    int rlo = blockIdx.x << shift;
    int rhi = min(rlo + rows, N);
    for (int i = t; i < rows; i += 256) lcnt[i] = 0;
    __syncthreads();
    int base = row_ptr[rlo], end = row_ptr[rhi];
    for (int i = base + t; i < end; i += 256) {
        int2 ent = grouped[i];
        int pos = atomicAdd(&lcnt[ent.y - rlo], 1);
        packed[row_ptr[ent.y] + pos] = make_int2(ent.x, __float_as_int(dinv[ent.x]));
    }
}

// ---------------- weight convert: fragment-ordered W1f/W2f in bf16 ----------

__global__ __launch_bounds__(256) void k_convert(const float* __restrict__ W1,
                                                 const float* __restrict__ W2,
                                                 unsigned short* __restrict__ W1f,
                                                 unsigned short* __restrict__ W2f) {
    int idx = blockIdx.x * 256 + threadIdx.x;
    if (idx < 65536) {
        int g = idx >> 9, r = idx & 511;
        int l = r >> 3, j = r & 7;
        int n = (g >> 3) * 16 + (l & 15);
        int k = (g & 7) * 32 + (l >> 4) * 8 + j;
        W1f[idx] = f2bf(W1[k * 256 + n]);
    }
    int i2 = idx - 65536;
    if (i2 >= 0 && i2 < 16384) {
        int g = i2 >> 9, r = i2 & 511;
        int l = r >> 3, j = r & 7;
        int n = (g >> 3) * 16 + (l & 15);
        int k = (g & 7) * 32 + (l >> 4) * 8 + j;
        W2f[i2] = f2bf(W2[k * 64 + n]);
    }
}

// ---------------- x convert: fp32 row-major -> bf16 tile-major swizzled ------

__global__ __launch_bounds__(256) void k_xconv(const float* __restrict__ x,
                                               unsigned short* __restrict__ xb,
                                               int N, long total_f4) {
    long f4 = (long)blockIdx.x * 256 + threadIdx.x;
    if (f4 >= total_f4) return;
    int row = (int)(f4 >> 6);
    int c4 = ((int)f4 & 63) << 2;
    float4 v = make_float4(0.f, 0.f, 0.f, 0.f);
    if (row < N) v = *(const float4*)(x + (size_t)row * 256 + c4);
    int tb = row >> 6, r = row & 63;
    int e = (r * 256 + c4) ^ ((r & 7) << 3);
    ushort4 pk;
    pk.x = f2bf(v.x); pk.y = f2bf(v.y); pk.z = f2bf(v.z); pk.w = f2bf(v.w);
    *(ushort4*)&xb[(size_t)tb * 16384 + e] = pk;
}

// ---------------- MFMA MLP: writes h0/hA in COLUMN-BLOCKED layout ------------
// h layout: 4 blocks of [N][16] bf16; col = nt*16+lr -> block nt, idx lr.

__global__ __launch_bounds__(256) void k_mlp_fast(const unsigned short* __restrict__ xb,
                                                  const unsigned short* __restrict__ W1f,
                                                  const float* __restrict__ b1,
                                                  const unsigned short* __restrict__ W2f,
                                                  const float* __restrict__ b2,
                                                  unsigned short* __restrict__ h0b,
                                                  unsigned short* __restrict__ hAb,
                                                  int N) {
    __shared__ unsigned short xs[64 * 256];
    int t = threadIdx.x;
    int base = blockIdx.x * 64;
    int w  = t >> 6;
    int l  = t & 63;
    int lr = l & 15;
    int lk = l >> 4;
    size_t nb16 = (size_t)N * 16;

    const char* gsrc = (const char*)(xb + (size_t)blockIdx.x * 16384);
    char* lbase = (char*)&xs[0];
    #pragma unroll
    for (int i = 0; i < 8; ++i) {
        int off = ((i << 2) + w) * 1024 + l * 16;
        __builtin_amdgcn_global_load_lds((gu32*)(gsrc + off), (lu32*)(lbase + off),
                                         16, 0, 0);
    }
    __syncthreads();

    floatx4 acc[4][4];
    #pragma unroll
    for (int mt = 0; mt < 4; ++mt)
        #pragma unroll
        for (int nt = 0; nt < 4; ++nt)
            acc[mt][nt] = (floatx4){0.f, 0.f, 0.f, 0.f};

    #pragma unroll
    for (int kc = 0; kc < 8; ++kc) {
        short8 af[4], bf[4];
        #pragma unroll
        for (int mt = 0; mt < 4; ++mt) {
            int m = mt * 16 + lr;
            int e = (m * 256 + kc * 32 + lk * 8) ^ ((m & 7) << 3);
            af[mt] = *(const short8*)&xs[e];
        }
        #pragma unroll
        for (int nt = 0; nt < 4; ++nt) {
            int g = (w * 4 + nt) * 8 + kc;
            bf[nt] = *(const short8*)&W1f[g * 512 + l * 8];
        }
        #pragma unroll
        for (int mt = 0; mt < 4; ++mt)
            #pragma unroll
            for (int nt = 0; nt < 4; ++nt)
                acc[mt][nt] = __builtin_amdgcn_mfma_f32_16x16x32_bf16(
                    af[mt], bf[nt], acc[mt][nt], 0, 0, 0);
    }

    float b1v[4];
    #pragma unroll
    for (int nt = 0; nt < 4; ++nt) b1v[nt] = b1[w * 64 + nt * 16 + lr];

    __syncthreads();
    #pragma unroll
    for (int mt = 0; mt < 4; ++mt)
        #pragma unroll
        for (int nt = 0; nt < 4; ++nt)
            #pragma unroll
            for (int r = 0; r < 4; ++r) {
                int m = mt * 16 + lk * 4 + r;
                int n = w * 64 + nt * 16 + lr;
                float hv = fmaxf(acc[mt][nt][r] + b1v[nt], 0.f);
                xs[(m * 256 + n) ^ ((m & 7) << 3)] = f2bf(hv);
            }
    __syncthreads();

    floatx4 acc2[4];
    #pragma unroll
    for (int nt = 0; nt < 4; ++nt) acc2[nt] = (floatx4){0.f, 0.f, 0.f, 0.f};

    #pragma unroll
    for (int kc = 0; kc < 8; ++kc) {
        int m = w * 16 + lr;
        int e = (m * 256 + kc * 32 + lk * 8) ^ ((m & 7) << 3);
        short8 af = *(const short8*)&xs[e];
        #pragma unroll
        for (int nt = 0; nt < 4; ++nt) {
            int g = nt * 8 + kc;
            short8 bf_ = *(const short8*)&W2f[g * 512 + l * 8];
            acc2[nt] = __builtin_amdgcn_mfma_f32_16x16x32_bf16(
                af, bf_, acc2[nt], 0, 0, 0);
        }
    }

    float b2v[4];
    #pragma unroll
    for (int nt = 0; nt < 4; ++nt) b2v[nt] = b2[nt * 16 + lr];

    #pragma unroll
    for (int nt = 0; nt < 4; ++nt)
        #pragma unroll
        for (int r = 0; r < 4; ++r) {
            int rg = base + w * 16 + lk * 4 + r;
            if (rg < N) {
                size_t a = (size_t)nt * nb16 + (size_t)rg * 16 + lr;
                unsigned short bv = f2bf(acc2[nt][r] + b2v[nt]);
                h0b[a] = bv;
                hAb[a] = bv;
            }
        }
}

// Slow path (fragment weights, blocked h output), used if ws too small for xb.
__global__ __launch_bounds__(256) void k_mlp_slow(const float* __restrict__ x,
                                                  const unsigned short* __restrict__ W1f,
                                                  const float* __restrict__ b1,
                                                  const unsigned short* __restrict__ W2f,
                                                  const float* __restrict__ b2,
                                                  unsigned short* __restrict__ h0b,
                                                  unsigned short* __restrict__ hAb,
                                                  int N) {
    __shared__ unsigned short xs[64 * 256];
    int t = threadIdx.x;
    int base = blockIdx.x * 64;
    int w  = t >> 6;
    int l  = t & 63;
    int lr = l & 15;
    int lk = l >> 4;
    size_t nb16 = (size_t)N * 16;

    #pragma unroll
    for (int pass = 0; pass < 16; ++pass) {
        int f = pass * 256 + t;
        int r = f >> 6;
        int c4 = (f & 63) << 2;
        float4 v = make_float4(0.f, 0.f, 0.f, 0.f);
        int row = base + r;
        if (row < N) v = *(const float4*)(x + (size_t)row * 256 + c4);
        int e = (r * 256 + c4) ^ ((r & 7) << 3);
        ushort4 pk;
        pk.x = f2bf(v.x); pk.y = f2bf(v.y); pk.z = f2bf(v.z); pk.w = f2bf(v.w);
        *(ushort4*)&xs[e] = pk;
    }
    __syncthreads();

    floatx4 acc[4][4];
    #pragma unroll
    for (int mt = 0; mt < 4; ++mt)
        #pragma unroll
        for (int nt = 0; nt < 4; ++nt)
            acc[mt][nt] = (floatx4){0.f, 0.f, 0.f, 0.f};

    #pragma unroll
    for (int kc = 0; kc < 8; ++kc) {
        short8 af[4], bf[4];
        #pragma unroll
        for (int mt = 0; mt < 4; ++mt) {
            int m = mt * 16 + lr;
            int e = (m * 256 + kc * 32 + lk * 8) ^ ((m & 7) << 3);
            af[mt] = *(const short8*)&xs[e];
        }
        #pragma unroll
        for (int nt = 0; nt < 4; ++nt) {
            int g = (w * 4 + nt) * 8 + kc;
            bf[nt] = *(const short8*)&W1f[g * 512 + l * 8];
        }
        #pragma unroll
        for (int mt = 0; mt < 4; ++mt)
            #pragma unroll
            for (int nt = 0; nt < 4; ++nt)
                acc[mt][nt] = __builtin_amdgcn_mfma_f32_16x16x32_bf16(
                    af[mt], bf[nt], acc[mt][nt], 0, 0, 0);
    }

    float b1v[4];
    #pragma unroll
    for (int nt = 0; nt < 4; ++nt) b1v[nt] = b1[w * 64 + nt * 16 + lr];

    __syncthreads();
    #pragma unroll
    for (int mt = 0; mt < 4; ++mt)
        #pragma unroll
        for (int nt = 0; nt < 4; ++nt)
            #pragma unroll
            for (int r = 0; r < 4; ++r) {
                int m = mt * 16 + lk * 4 + r;
                int n = w * 64 + nt * 16 + lr;
                float hv = fmaxf(acc[mt][nt][r] + b1v[nt], 0.f);
                xs[(m * 256 + n) ^ ((m & 7) << 3)] = f2bf(hv);
            }
    __syncthreads();

    floatx4 acc2[4];
    #pragma unroll
    for (int nt = 0; nt < 4; ++nt) acc2[nt] = (floatx4){0.f, 0.f, 0.f, 0.f};

    #pragma unroll
    for (int kc = 0; kc < 8; ++kc) {
        int m = w * 16 + lr;
        int e = (m * 256 + kc * 32 + lk * 8) ^ ((m & 7) << 3);
        short8 af = *(const short8*)&xs[e];
        #pragma unroll
        for (int nt = 0; nt < 4; ++nt) {
            int g = nt * 8 + kc;
            short8 bf_ = *(const short8*)&W2f[g * 512 + l * 8];
            acc2[nt] = __builtin_amdgcn_mfma_f32_16x16x32_bf16(
                af, bf_, acc2[nt], 0, 0, 0);
        }
    }

    float b2v[4];
    #pragma unroll
    for (int nt = 0; nt < 4; ++nt) b2v[nt] = b2[nt * 16 + lr];

    #pragma unroll
    for (int nt = 0; nt < 4; ++nt)
        #pragma unroll
        for (int r = 0; r < 4; ++r) {
            int rg = base + w * 16 + lk * 4 + r;
            if (rg < N) {
                size_t a = (size_t)nt * nb16 + (size_t)rg * 16 + lr;
                unsigned short bv = f2bf(acc2[nt][r] + b2v[nt]);
                h0b[a] = bv;
                hAb[a] = bv;
            }
        }
}

// ---------------- propagation: column-blocked (L2-resident gather) ----------
// h layout: 4 blocks of [N][16] bf16 (3.2 MB each, fits per-XCD L2).
// Grid = 4*RB; cb = blockIdx/RB. 4-lane group per row, lane holds 4 cols
// (ushort4 8B loads); 16 rows/wave; descriptor chunks of 4, double-buffered.

__global__ __launch_bounds__(256) void k_prop(const unsigned short* __restrict__ h_in,
                                              unsigned short* __restrict__ h_out,
                                              const unsigned short* __restrict__ h0,
                                              const int* __restrict__ row_ptr,
                                              const int2* __restrict__ packed,
                                              const float* __restrict__ dinv,
                                              int N, int RB) {
    int tid = threadIdx.x;
    int lane = tid & 63;
    int gl = lane & 3;                         // lane within 4-lane group
    int cb = blockIdx.x / RB;
    int rblk = blockIdx.x - cb * RB;
    int row = rblk * 64 + (tid >> 2);
    bool valid = row < N;
    int rbase = valid ? row : 0;

    const unsigned short* hb  = h_in + (size_t)cb * N * 16;
    unsigned short*       ob  = h_out + (size_t)cb * N * 16;
    const unsigned short* h0b = h0 + (size_t)cb * N * 16;

    float dv = dinv[rbase];
    int p = row_ptr[rbase];
    int deg = valid ? (row_ptr[rbase + 1] - p) : 0;

    ushort4 sv  = *(const ushort4*)&hb[(size_t)rbase * 16 + gl * 4];
    ushort4 h0v = *(const ushort4*)&h0b[(size_t)rbase * 16 + gl * 4];

    int deg_max = deg;
    deg_max = max(deg_max, __shfl_xor(deg_max, 4));
    deg_max = max(deg_max, __shfl_xor(deg_max, 8));
    deg_max = max(deg_max, __shfl_xor(deg_max, 16));
    deg_max = max(deg_max, __shfl_xor(deg_max, 32));

    float a0 = 0.f, a1 = 0.f, a2 = 0.f, a3 = 0.f;

    int2 d = make_int2(0, 0);
    if (gl < deg) d = packed[p + gl];
    for (int b = 0; b < deg_max; b += 4) {
        int2 dn = make_int2(0, 0);
        int bn = b + 4;
        if (bn < deg_max && bn + gl < deg) dn = packed[p + bn + gl];
        #pragma unroll
        for (int u = 0; u < 4; ++u) {
            int idx = (lane & 60) + u;
            int s = __shfl(d.x, idx);
            float wgt = __int_as_float(__shfl(d.y, idx));
            if (b + u < deg) {                 // group-uniform predicate
                ushort4 hv = *(const ushort4*)&hb[(size_t)s * 16 + gl * 4];
                a0 += wgt * bf2f(hv.x);
                a1 += wgt * bf2f(hv.y);
                a2 += wgt * bf2f(hv.z);
                a3 += wgt * bf2f(hv.w);
            }
        }
        d = dn;
    }

    float c = (1.0f - ALPHA) * dv;
    float v0 = c * (a0 + dv * bf2f(sv.x)) + ALPHA * bf2f(h0v.x);
    float v1 = c * (a1 + dv * bf2f(sv.y)) + ALPHA * bf2f(h0v.y);
    float v2 = c * (a2 + dv * bf2f(sv.z)) + ALPHA * bf2f(h0v.z);
    float v3 = c * (a3 + dv * bf2f(sv.w)) + ALPHA * bf2f(h0v.w);

    if (valid) {
        ushort4 o;
        o.x = f2bf(v0); o.y = f2bf(v1); o.z = f2bf(v2); o.w = f2bf(v3);
        *(ushort4*)&ob[(size_t)row * 16 + gl * 4] = o;
    }
}

// ---------------- final log-softmax from blocked bf16 h ----------------------
// 16 lanes per row; lane l reads col l of each of the 4 blocks.

__global__ __launch_bounds__(256) void k_lsm(const unsigned short* __restrict__ h,
                                             float* __restrict__ out, int N) {
    int tid = threadIdx.x;
    int l = tid & 15;
    int row = blockIdx.x * 16 + (tid >> 4);
    bool valid = row < N;
    int rbase = valid ? row : 0;
    size_t nb16 = (size_t)N * 16;

    float v[4];
    #pragma unroll
    for (int cb = 0; cb < 4; ++cb)
        v[cb] = bf2f(h[(size_t)cb * nb16 + (size_t)rbase * 16 + l]);

    float mx = fmaxf(fmaxf(v[0], v[1]), fmaxf(v[2], v[3]));
    #pragma unroll
    for (int o = 8; o; o >>= 1) mx = fmaxf(mx, __shfl_xor(mx, o));
    float es = __expf(v[0] - mx) + __expf(v[1] - mx)
             + __expf(v[2] - mx) + __expf(v[3] - mx);
    #pragma unroll
    for (int o = 8; o; o >>= 1) es += __shfl_xor(es, o);
    float lse = mx + logf(es);

    if (valid) {
        #pragma unroll
        for (int cb = 0; cb < 4; ++cb)
            out[(size_t)row * 64 + cb * 16 + l] = v[cb] - lse;
    }
}

// ---------------- launch ----------------

extern "C" void kernel_launch(void* const* d_in, const int* in_sizes, int n_in,
                              void* d_out, int out_size, void* d_ws, size_t ws_size,
                              hipStream_t stream) {
    const float* x  = (const float*)d_in[0];
    const int*   ei = (const int*)d_in[1];
    const float* W1 = (const float*)d_in[2];
    const float* b1 = (const float*)d_in[3];
    const float* W2 = (const float*)d_in[4];
    const float* b2 = (const float*)d_in[5];
    float* out = (float*)d_out;

    int N = in_sizes[0] / 256;
    int E = in_sizes[1] / 2;
    int nblk = (N + 1023) / 1024;
    int ntiles = (N + 63) / 64;
    int RB = (N + 63) / 64;

    int shift = 0;
    while ((((long)N - 1) >> shift) >= 256) shift++;
    int NB = (int)(((long)(N - 1) >> shift) + 1);

    char* ws = (char*)d_ws;
    size_t off = 0;
    auto carve = [&](size_t bytes) -> void* {
        void* p = ws + off;
        off += (bytes + 255) & ~(size_t)255;
        return p;
    };
    int*            cnt     = (int*)carve((size_t)N * 4);
    int*            row_ptr = (int*)carve((size_t)(N + 1) * 4);
    int*            partial = (int*)carve((size_t)nblk * 4);
    int*            blkoff  = (int*)carve((size_t)nblk * 4);
    int*            bcnt    = (int*)carve(256 * 4);
    int*            boff    = (int*)carve(257 * 4);
    int*            gcur    = (int*)carve((size_t)NB * 4);
    float*          dinv    = (float*)carve((size_t)N * 4);
    int2*           packed  = (int2*)carve((size_t)E * 8);
    unsigned short* W1f     = (unsigned short*)carve(256 * 256 * 2);
    unsigned short* W2f     = (unsigned short*)carve(64 * 256 * 2);
    unsigned short* h0b     = (unsigned short*)carve((size_t)N * 64 * 2);
    unsigned short* hAb     = (unsigned short*)carve((size_t)N * 64 * 2);
    unsigned short* hBb     = (unsigned short*)carve((size_t)N * 64 * 2);
    int2*           grouped = (int2*)carve((size_t)E * 8);

    size_t xb_bytes = (size_t)ntiles * 16384 * 2;
    size_t grouped_sz = ((size_t)E * 8 + 255) & ~(size_t)255;
    unsigned short* xb = nullptr;
    if (xb_bytes <= grouped_sz) {
        xb = (unsigned short*)grouped;
    } else if (off + (xb_bytes - grouped_sz) + 256 <= ws_size) {
        carve(xb_bytes - grouped_sz);
        xb = (unsigned short*)grouped;
    }

    hipMemsetAsync(bcnt, 0, 256 * 4, stream);
    hipMemsetAsync(gcur, 0, (size_t)NB * 4, stream);

    k_bcount<<<256, 256, 0, stream>>>(ei, E, shift, bcnt);
    k_boff<<<1, 256, 0, stream>>>(bcnt, boff);
    int bgrid = (int)(((long)E + CHUNK - 1) / CHUNK);
    k_bucket2<<<bgrid, 256, 0, stream>>>(ei, E, boff, gcur, grouped, shift, NB);
    k_rowcnt<<<NB, 256, 0, stream>>>(grouped, boff, cnt, dinv, shift, N);
    k_scan_part<<<nblk, 256, 0, stream>>>(cnt, partial, N);
    k_scan_off<<<1, 128, 0, stream>>>(partial, blkoff, row_ptr + N, nblk);
    k_scan_write<<<nblk, 256, 0, stream>>>(cnt, blkoff, row_ptr, N);
    k_fill2<<<NB, 256, 0, stream>>>(grouped, row_ptr, dinv, packed, shift, N);
    k_convert<<<320, 256, 0, stream>>>(W1, W2, W1f, W2f);

    if (xb) {
        long total_f4 = (long)ntiles * 64 * 64;
        int xg = (int)((total_f4 + 255) / 256);
        k_xconv<<<xg, 256, 0, stream>>>(x, xb, N, total_f4);
        k_mlp_fast<<<ntiles, 256, 0, stream>>>(xb, W1f, b1, W2f, b2, h0b, hAb, N);
    } else {
        k_mlp_slow<<<ntiles, 256, 0, stream>>>(x, W1f, b1, W2f, b2, h0b, hAb, N);
    }

    const unsigned short* hin = hAb;
    unsigned short* hout = hBb;
    for (int it = 0; it < K_ITERS; ++it) {
        k_prop<<<4 * RB, 256, 0, stream>>>(hin, hout, h0b, row_ptr, packed,
                                           dinv, N, RB);
        const unsigned short* tmp = hin;
        hin = hout;
        hout = (unsigned short*)tmp;
    }
    k_lsm<<<(N + 15) / 16, 256, 0, stream>>>(hin, out, N);
}

// Round 18
// 517.262 us; speedup vs baseline: 1.9759x; 1.9759x over previous
//
#include <hip/hip_runtime.h>
#include <hip/hip_bf16.h>
#include <math.h>

#define ALPHA 0.1f
#define K_ITERS 10
#define CHUNK 4096
#define PER_TH 16

typedef __attribute__((ext_vector_type(8))) short short8;
typedef __attribute__((ext_vector_type(4))) float floatx4;
typedef const __attribute__((address_space(1))) unsigned int gu32;
typedef __attribute__((address_space(3))) unsigned int lu32;

static __device__ __forceinline__ float bf2f(unsigned short u) {
    union { unsigned int i; float f; } v;
    v.i = ((unsigned int)u) << 16;
    return v.f;
}
static __device__ __forceinline__ unsigned short f2bf(float f) {
    union { float f; unsigned int i; } v;
    v.f = f;
    unsigned int r = v.i + 0x7FFF + ((v.i >> 16) & 1);   // round-nearest-even
    return (unsigned short)(r >> 16);
}

// ---------------- CSR build (no N-wide random atomics anywhere) ----------------

__global__ __launch_bounds__(256) void k_bcount(const int* __restrict__ ei, int E,
                                                int shift, int* __restrict__ bcnt) {
    __shared__ int h[256];
    h[threadIdx.x] = 0;
    __syncthreads();
    int stride = gridDim.x * blockDim.x;
    for (int e = blockIdx.x * blockDim.x + threadIdx.x; e < E; e += stride)
        atomicAdd(&h[ei[E + e] >> shift], 1);
    __syncthreads();
    if (h[threadIdx.x]) atomicAdd(&bcnt[threadIdx.x], h[threadIdx.x]);
}

__global__ __launch_bounds__(256) void k_boff(const int* __restrict__ bcnt,
                                              int* __restrict__ boff) {
    __shared__ int sc[256];
    int t = threadIdx.x;
    sc[t] = bcnt[t];
    __syncthreads();
    for (int o = 1; o < 256; o <<= 1) {
        int w = (t >= o) ? sc[t - o] : 0;
        __syncthreads();
        sc[t] += w;
        __syncthreads();
    }
    boff[t] = t ? sc[t - 1] : 0;
    if (t == 255) boff[256] = sc[255];   // == E
}

__global__ __launch_bounds__(256) void k_bucket2(const int* __restrict__ ei, int E,
                                                 const int* __restrict__ boff,
                                                 int* __restrict__ gcur,
                                                 int2* __restrict__ grouped,
                                                 int shift, int NB) {
    __shared__ int hist[256];
    __shared__ int sc[256];
    __shared__ int cursor[256];
    __shared__ int gdst[256];
    __shared__ int2 stage[CHUNK];
    int t = threadIdx.x;
    long e0 = (long)blockIdx.x * CHUNK;
    int total = (int)min((long)CHUNK, (long)E - e0);

    int sarr[PER_TH], darr[PER_TH];
    #pragma unroll
    for (int i = 0; i < PER_TH; ++i) {
        long e = e0 + t + i * 256;
        if (e < E) { sarr[i] = ei[e]; darr[i] = ei[E + e]; }
        else { sarr[i] = 0; darr[i] = -1; }
    }
    hist[t] = 0;
    __syncthreads();
    #pragma unroll
    for (int i = 0; i < PER_TH; ++i)
        if (darr[i] >= 0) atomicAdd(&hist[darr[i] >> shift], 1);
    __syncthreads();
    sc[t] = hist[t];
    __syncthreads();
    for (int o = 1; o < 256; o <<= 1) {
        int w = (t >= o) ? sc[t - o] : 0;
        __syncthreads();
        sc[t] += w;
        __syncthreads();
    }
    cursor[t] = sc[t] - hist[t];
    __syncthreads();
    #pragma unroll
    for (int i = 0; i < PER_TH; ++i)
        if (darr[i] >= 0) {
            int b = darr[i] >> shift;
            int pos = atomicAdd(&cursor[b], 1);
            stage[pos] = make_int2(sarr[i], darr[i]);
        }
    if (t < NB && hist[t] > 0)
        gdst[t] = boff[t] + atomicAdd(&gcur[t], hist[t]);
    __syncthreads();
    for (int i = t; i < total; i += 256) {
        int2 ent = stage[i];
        int b = ent.y >> shift;
        int r = i - (sc[b] - hist[b]);
        grouped[gdst[b] + r] = ent;
    }
}

__global__ __launch_bounds__(256) void k_rowcnt(const int2* __restrict__ grouped,
                                                const int* __restrict__ boff,
                                                int* __restrict__ cnt,
                                                float* __restrict__ dinv,
                                                int shift, int N) {
    __shared__ int lcnt[1024];
    int t = threadIdx.x;
    int rows = 1 << shift;
    int rlo = blockIdx.x << shift;
    int rhi = min(rlo + rows, N);
    for (int i = t; i < rows; i += 256) lcnt[i] = 0;
    __syncthreads();
    int base = boff[blockIdx.x], end = boff[blockIdx.x + 1];
    for (int i = base + t; i < end; i += 256)
        atomicAdd(&lcnt[grouped[i].y - rlo], 1);
    __syncthreads();
    for (int i = rlo + t; i < rhi; i += 256) {
        int c = lcnt[i - rlo];
        cnt[i] = c;
        dinv[i] = rsqrtf((float)(c + 1));   // +1 self loop
    }
}

// ---- parallel exclusive scan of cnt -> row_ptr ----

__global__ __launch_bounds__(256) void k_scan_part(const int* __restrict__ cnt,
                                                   int* __restrict__ partial, int N) {
    __shared__ int red[256];
    int t = threadIdx.x;
    int base = blockIdx.x * 1024 + t * 4;
    int s = 0;
    #pragma unroll
    for (int u = 0; u < 4; ++u) { int i = base + u; if (i < N) s += cnt[i]; }
    red[t] = s;
    __syncthreads();
    for (int o = 128; o; o >>= 1) {
        if (t < o) red[t] += red[t + o];
        __syncthreads();
    }
    if (t == 0) partial[blockIdx.x] = red[0];
}

__global__ __launch_bounds__(128) void k_scan_off(const int* __restrict__ partial,
                                                  int* __restrict__ blkoff,
                                                  int* __restrict__ row_ptr_last,
                                                  int nblk) {
    __shared__ int sc[128];
    int t = threadIdx.x;
    sc[t] = (t < nblk) ? partial[t] : 0;
    __syncthreads();
    for (int o = 1; o < 128; o <<= 1) {
        int w = (t >= o) ? sc[t - o] : 0;
        __syncthreads();
        sc[t] += w;
        __syncthreads();
    }
    if (t < nblk) blkoff[t] = t ? sc[t - 1] : 0;
    if (t == 127) *row_ptr_last = sc[127];
}

__global__ __launch_bounds__(256) void k_scan_write(const int* __restrict__ cnt,
                                                    const int* __restrict__ blkoff,
                                                    int* __restrict__ row_ptr, int N) {
    __shared__ int sc[256];
    int t = threadIdx.x;
    int base = blockIdx.x * 1024 + t * 4;
    int c[4];
    int s = 0;
    #pragma unroll
    for (int u = 0; u < 4; ++u) {
        int i = base + u;
        c[u] = (i < N) ? cnt[i] : 0;
        s += c[u];
    }
    sc[t] = s;
    __syncthreads();
    for (int o = 1; o < 256; o <<= 1) {
        int w = (t >= o) ? sc[t - o] : 0;
        __syncthreads();
        sc[t] += w;
        __syncthreads();
    }
    int run = blkoff[blockIdx.x] + (t ? sc[t - 1] : 0);
    #pragma unroll
    for (int u = 0; u < 4; ++u) {
        int i = base + u;
        if (i < N) { row_ptr[i] = run; run += c[u]; }
    }
}

__global__ __launch_bounds__(256) void k_fill2(const int2* __restrict__ grouped,
                                               const int* __restrict__ row_ptr,
                                               const float* __restrict__ dinv,
                                               int2* __restrict__ packed,
                                               int shift, int N) {
    __shared__ int lcnt[1024];
    int t = threadIdx.x;
    int rows = 1 << shift;
    int rlo = blockIdx.x << shift;
    int rhi = min(rlo + rows, N);
    for (int i = t; i < rows; i += 256) lcnt[i] = 0;
    __syncthreads();
    int base = row_ptr[rlo], end = row_ptr[rhi];
    for (int i = base + t; i < end; i += 256) {
        int2 ent = grouped[i];
        int pos = atomicAdd(&lcnt[ent.y - rlo], 1);
        packed[row_ptr[ent.y] + pos] = make_int2(ent.x, __float_as_int(dinv[ent.x]));
    }
}

// ---------------- weight convert: fragment-ordered W1f/W2f in bf16 ----------

__global__ __launch_bounds__(256) void k_convert(const float* __restrict__ W1,
                                                 const float* __restrict__ W2,
                                                 unsigned short* __restrict__ W1f,
                                                 unsigned short* __restrict__ W2f) {
    int idx = blockIdx.x * 256 + threadIdx.x;
    if (idx < 65536) {
        int g = idx >> 9, r = idx & 511;
        int l = r >> 3, j = r & 7;
        int n = (g >> 3) * 16 + (l & 15);
        int k = (g & 7) * 32 + (l >> 4) * 8 + j;
        W1f[idx] = f2bf(W1[k * 256 + n]);
    }
    int i2 = idx - 65536;
    if (i2 >= 0 && i2 < 16384) {
        int g = i2 >> 9, r = i2 & 511;
        int l = r >> 3, j = r & 7;
        int n = (g >> 3) * 16 + (l & 15);
        int k = (g & 7) * 32 + (l >> 4) * 8 + j;
        W2f[i2] = f2bf(W2[k * 64 + n]);
    }
}

// ---------------- x convert: fp32 row-major -> bf16 tile-major swizzled ------

__global__ __launch_bounds__(256) void k_xconv(const float* __restrict__ x,
                                               unsigned short* __restrict__ xb,
                                               int N, long total_f4) {
    long f4 = (long)blockIdx.x * 256 + threadIdx.x;
    if (f4 >= total_f4) return;
    int row = (int)(f4 >> 6);
    int c4 = ((int)f4 & 63) << 2;
    float4 v = make_float4(0.f, 0.f, 0.f, 0.f);
    if (row < N) v = *(const float4*)(x + (size_t)row * 256 + c4);
    int tb = row >> 6, r = row & 63;
    int e = (r * 256 + c4) ^ ((r & 7) << 3);
    ushort4 pk;
    pk.x = f2bf(v.x); pk.y = f2bf(v.y); pk.z = f2bf(v.z); pk.w = f2bf(v.w);
    *(ushort4*)&xb[(size_t)tb * 16384 + e] = pk;
}

// ---------------- MFMA MLP: h0 = relu(x@W1+b1)@W2+b2 (bf16 in, fp32 acc) -----
// Row-major h output (reverted from round-17 blocked layout).

__global__ __launch_bounds__(256) void k_mlp_fast(const unsigned short* __restrict__ xb,
                                                  const unsigned short* __restrict__ W1f,
                                                  const float* __restrict__ b1,
                                                  const unsigned short* __restrict__ W2f,
                                                  const float* __restrict__ b2,
                                                  unsigned short* __restrict__ h0b,
                                                  unsigned short* __restrict__ hAb,
                                                  int N) {
    __shared__ unsigned short xs[64 * 256];
    int t = threadIdx.x;
    int base = blockIdx.x * 64;
    int w  = t >> 6;
    int l  = t & 63;
    int lr = l & 15;
    int lk = l >> 4;

    const char* gsrc = (const char*)(xb + (size_t)blockIdx.x * 16384);
    char* lbase = (char*)&xs[0];
    #pragma unroll
    for (int i = 0; i < 8; ++i) {
        int off = ((i << 2) + w) * 1024 + l * 16;
        __builtin_amdgcn_global_load_lds((gu32*)(gsrc + off), (lu32*)(lbase + off),
                                         16, 0, 0);
    }
    __syncthreads();

    floatx4 acc[4][4];
    #pragma unroll
    for (int mt = 0; mt < 4; ++mt)
        #pragma unroll
        for (int nt = 0; nt < 4; ++nt)
            acc[mt][nt] = (floatx4){0.f, 0.f, 0.f, 0.f};

    #pragma unroll
    for (int kc = 0; kc < 8; ++kc) {
        short8 af[4], bf[4];
        #pragma unroll
        for (int mt = 0; mt < 4; ++mt) {
            int m = mt * 16 + lr;
            int e = (m * 256 + kc * 32 + lk * 8) ^ ((m & 7) << 3);
            af[mt] = *(const short8*)&xs[e];
        }
        #pragma unroll
        for (int nt = 0; nt < 4; ++nt) {
            int g = (w * 4 + nt) * 8 + kc;
            bf[nt] = *(const short8*)&W1f[g * 512 + l * 8];
        }
        #pragma unroll
        for (int mt = 0; mt < 4; ++mt)
            #pragma unroll
            for (int nt = 0; nt < 4; ++nt)
                acc[mt][nt] = __builtin_amdgcn_mfma_f32_16x16x32_bf16(
                    af[mt], bf[nt], acc[mt][nt], 0, 0, 0);
    }

    float b1v[4];
    #pragma unroll
    for (int nt = 0; nt < 4; ++nt) b1v[nt] = b1[w * 64 + nt * 16 + lr];

    __syncthreads();
    #pragma unroll
    for (int mt = 0; mt < 4; ++mt)
        #pragma unroll
        for (int nt = 0; nt < 4; ++nt)
            #pragma unroll
            for (int r = 0; r < 4; ++r) {
                int m = mt * 16 + lk * 4 + r;
                int n = w * 64 + nt * 16 + lr;
                float hv = fmaxf(acc[mt][nt][r] + b1v[nt], 0.f);
                xs[(m * 256 + n) ^ ((m & 7) << 3)] = f2bf(hv);
            }
    __syncthreads();

    floatx4 acc2[4];
    #pragma unroll
    for (int nt = 0; nt < 4; ++nt) acc2[nt] = (floatx4){0.f, 0.f, 0.f, 0.f};

    #pragma unroll
    for (int kc = 0; kc < 8; ++kc) {
        int m = w * 16 + lr;
        int e = (m * 256 + kc * 32 + lk * 8) ^ ((m & 7) << 3);
        short8 af = *(const short8*)&xs[e];
        #pragma unroll
        for (int nt = 0; nt < 4; ++nt) {
            int g = nt * 8 + kc;
            short8 bf_ = *(const short8*)&W2f[g * 512 + l * 8];
            acc2[nt] = __builtin_amdgcn_mfma_f32_16x16x32_bf16(
                af, bf_, acc2[nt], 0, 0, 0);
        }
    }

    float b2v[4];
    #pragma unroll
    for (int nt = 0; nt < 4; ++nt) b2v[nt] = b2[nt * 16 + lr];

    #pragma unroll
    for (int nt = 0; nt < 4; ++nt)
        #pragma unroll
        for (int r = 0; r < 4; ++r) {
            int rg = base + w * 16 + lk * 4 + r;
            if (rg < N) {
                int col = nt * 16 + lr;
                unsigned short bv = f2bf(acc2[nt][r] + b2v[nt]);
                h0b[(size_t)rg * 64 + col] = bv;
                hAb[(size_t)rg * 64 + col] = bv;
            }
        }
}

// Slow path (fragment weights, row-major h), used if ws too small for xb.
__global__ __launch_bounds__(256) void k_mlp_slow(const float* __restrict__ x,
                                                  const unsigned short* __restrict__ W1f,
                                                  const float* __restrict__ b1,
                                                  const unsigned short* __restrict__ W2f,
                                                  const float* __restrict__ b2,
                                                  unsigned short* __restrict__ h0b,
                                                  unsigned short* __restrict__ hAb,
                                                  int N) {
    __shared__ unsigned short xs[64 * 256];
    int t = threadIdx.x;
    int base = blockIdx.x * 64;
    int w  = t >> 6;
    int l  = t & 63;
    int lr = l & 15;
    int lk = l >> 4;

    #pragma unroll
    for (int pass = 0; pass < 16; ++pass) {
        int f = pass * 256 + t;
        int r = f >> 6;
        int c4 = (f & 63) << 2;
        float4 v = make_float4(0.f, 0.f, 0.f, 0.f);
        int row = base + r;
        if (row < N) v = *(const float4*)(x + (size_t)row * 256 + c4);
        int e = (r * 256 + c4) ^ ((r & 7) << 3);
        ushort4 pk;
        pk.x = f2bf(v.x); pk.y = f2bf(v.y); pk.z = f2bf(v.z); pk.w = f2bf(v.w);
        *(ushort4*)&xs[e] = pk;
    }
    __syncthreads();

    floatx4 acc[4][4];
    #pragma unroll
    for (int mt = 0; mt < 4; ++mt)
        #pragma unroll
        for (int nt = 0; nt < 4; ++nt)
            acc[mt][nt] = (floatx4){0.f, 0.f, 0.f, 0.f};

    #pragma unroll
    for (int kc = 0; kc < 8; ++kc) {
        short8 af[4], bf[4];
        #pragma unroll
        for (int mt = 0; mt < 4; ++mt) {
            int m = mt * 16 + lr;
            int e = (m * 256 + kc * 32 + lk * 8) ^ ((m & 7) << 3);
            af[mt] = *(const short8*)&xs[e];
        }
        #pragma unroll
        for (int nt = 0; nt < 4; ++nt) {
            int g = (w * 4 + nt) * 8 + kc;
            bf[nt] = *(const short8*)&W1f[g * 512 + l * 8];
        }
        #pragma unroll
        for (int mt = 0; mt < 4; ++mt)
            #pragma unroll
            for (int nt = 0; nt < 4; ++nt)
                acc[mt][nt] = __builtin_amdgcn_mfma_f32_16x16x32_bf16(
                    af[mt], bf[nt], acc[mt][nt], 0, 0, 0);
    }

    float b1v[4];
    #pragma unroll
    for (int nt = 0; nt < 4; ++nt) b1v[nt] = b1[w * 64 + nt * 16 + lr];

    __syncthreads();
    #pragma unroll
    for (int mt = 0; mt < 4; ++mt)
        #pragma unroll
        for (int nt = 0; nt < 4; ++nt)
            #pragma unroll
            for (int r = 0; r < 4; ++r) {
                int m = mt * 16 + lk * 4 + r;
                int n = w * 64 + nt * 16 + lr;
                float hv = fmaxf(acc[mt][nt][r] + b1v[nt], 0.f);
                xs[(m * 256 + n) ^ ((m & 7) << 3)] = f2bf(hv);
            }
    __syncthreads();

    floatx4 acc2[4];
    #pragma unroll
    for (int nt = 0; nt < 4; ++nt) acc2[nt] = (floatx4){0.f, 0.f, 0.f, 0.f};

    #pragma unroll
    for (int kc = 0; kc < 8; ++kc) {
        int m = w * 16 + lr;
        int e = (m * 256 + kc * 32 + lk * 8) ^ ((m & 7) << 3);
        short8 af = *(const short8*)&xs[e];
        #pragma unroll
        for (int nt = 0; nt < 4; ++nt) {
            int g = nt * 8 + kc;
            short8 bf_ = *(const short8*)&W2f[g * 512 + l * 8];
            acc2[nt] = __builtin_amdgcn_mfma_f32_16x16x32_bf16(
                af, bf_, acc2[nt], 0, 0, 0);
        }
    }

    float b2v[4];
    #pragma unroll
    for (int nt = 0; nt < 4; ++nt) b2v[nt] = b2[nt * 16 + lr];

    #pragma unroll
    for (int nt = 0; nt < 4; ++nt)
        #pragma unroll
        for (int r = 0; r < 4; ++r) {
            int rg = base + w * 16 + lk * 4 + r;
            if (rg < N) {
                int col = nt * 16 + lr;
                unsigned short bv = f2bf(acc2[nt][r] + b2v[nt]);
                h0b[(size_t)rg * 64 + col] = bv;
                hAb[(size_t)rg * 64 + col] = bv;
            }
        }
}

// ---------------- propagation (bf16 h, fp32 accum) — row-major, reverted -----
// 8 rows per wave, short8 (16B) per lane, descriptor double-buffer.
// Verified at ~43 us/iter (rounds 14-16).

__global__ __launch_bounds__(256) void k_prop(const unsigned short* __restrict__ h_in,
                                              unsigned short* __restrict__ h_out,
                                              const unsigned short* __restrict__ h0,
                                              const int* __restrict__ row_ptr,
                                              const int2* __restrict__ packed,
                                              const float* __restrict__ dinv,
                                              int N, int last,
                                              float* __restrict__ out) {
    int tid = threadIdx.x;
    int lane = tid & 63;
    int gl = lane & 7;                        // lane within 8-lane group
    int row = blockIdx.x * 32 + (tid >> 3);   // wave*8 + group
    bool valid = row < N;
    int rbase = valid ? row : 0;

    float dv = dinv[rbase];
    int p = row_ptr[rbase];
    int deg = valid ? (row_ptr[rbase + 1] - p) : 0;

    short8 sv  = *(const short8*)&h_in[(size_t)rbase * 64 + gl * 8];
    short8 h0v = *(const short8*)&h0[(size_t)rbase * 64 + gl * 8];

    int deg_max = deg;
    deg_max = max(deg_max, __shfl_xor(deg_max, 8));
    deg_max = max(deg_max, __shfl_xor(deg_max, 16));
    deg_max = max(deg_max, __shfl_xor(deg_max, 32));

    float a0 = 0.f, a1 = 0.f, a2 = 0.f, a3 = 0.f;
    float a4 = 0.f, a5 = 0.f, a6 = 0.f, a7 = 0.f;

    int2 d = make_int2(0, 0);
    if (gl < deg) d = packed[p + gl];
    for (int b = 0; b < deg_max; b += 8) {
        int2 dn = make_int2(0, 0);
        int bn = b + 8;
        if (bn < deg_max && bn + gl < deg) dn = packed[p + bn + gl];
        #pragma unroll
        for (int u = 0; u < 8; ++u) {
            int idx = (lane & 56) + u;
            int s = __shfl(d.x, idx);
            float wgt = __int_as_float(__shfl(d.y, idx));
            if (b + u < deg) {
                short8 hv = *(const short8*)&h_in[(size_t)s * 64 + gl * 8];
                a0 += wgt * bf2f((unsigned short)hv[0]);
                a1 += wgt * bf2f((unsigned short)hv[1]);
                a2 += wgt * bf2f((unsigned short)hv[2]);
                a3 += wgt * bf2f((unsigned short)hv[3]);
                a4 += wgt * bf2f((unsigned short)hv[4]);
                a5 += wgt * bf2f((unsigned short)hv[5]);
                a6 += wgt * bf2f((unsigned short)hv[6]);
                a7 += wgt * bf2f((unsigned short)hv[7]);
            }
        }
        d = dn;
    }

    float c = (1.0f - ALPHA) * dv;
    float v0 = c * (a0 + dv * bf2f((unsigned short)sv[0])) + ALPHA * bf2f((unsigned short)h0v[0]);
    float v1 = c * (a1 + dv * bf2f((unsigned short)sv[1])) + ALPHA * bf2f((unsigned short)h0v[1]);
    float v2 = c * (a2 + dv * bf2f((unsigned short)sv[2])) + ALPHA * bf2f((unsigned short)h0v[2]);
    float v3 = c * (a3 + dv * bf2f((unsigned short)sv[3])) + ALPHA * bf2f((unsigned short)h0v[3]);
    float v4 = c * (a4 + dv * bf2f((unsigned short)sv[4])) + ALPHA * bf2f((unsigned short)h0v[4]);
    float v5 = c * (a5 + dv * bf2f((unsigned short)sv[5])) + ALPHA * bf2f((unsigned short)h0v[5]);
    float v6 = c * (a6 + dv * bf2f((unsigned short)sv[6])) + ALPHA * bf2f((unsigned short)h0v[6]);
    float v7 = c * (a7 + dv * bf2f((unsigned short)sv[7])) + ALPHA * bf2f((unsigned short)h0v[7]);

    if (!last) {
        if (valid) {
            short8 o;
            o[0] = (short)f2bf(v0); o[1] = (short)f2bf(v1);
            o[2] = (short)f2bf(v2); o[3] = (short)f2bf(v3);
            o[4] = (short)f2bf(v4); o[5] = (short)f2bf(v5);
            o[6] = (short)f2bf(v6); o[7] = (short)f2bf(v7);
            *(short8*)&h_out[(size_t)row * 64 + gl * 8] = o;
        }
    } else {
        float mx = fmaxf(fmaxf(fmaxf(v0, v1), fmaxf(v2, v3)),
                         fmaxf(fmaxf(v4, v5), fmaxf(v6, v7)));
        #pragma unroll
        for (int o = 4; o; o >>= 1) mx = fmaxf(mx, __shfl_xor(mx, o));
        float es = __expf(v0 - mx) + __expf(v1 - mx) + __expf(v2 - mx)
                 + __expf(v3 - mx) + __expf(v4 - mx) + __expf(v5 - mx)
                 + __expf(v6 - mx) + __expf(v7 - mx);
        #pragma unroll
        for (int o = 4; o; o >>= 1) es += __shfl_xor(es, o);
        float lse = mx + logf(es);
        if (valid) {
            float4 oa, ob;
            oa.x = v0 - lse; oa.y = v1 - lse; oa.z = v2 - lse; oa.w = v3 - lse;
            ob.x = v4 - lse; ob.y = v5 - lse; ob.z = v6 - lse; ob.w = v7 - lse;
            *(float4*)&out[(size_t)row * 64 + gl * 8]     = oa;
            *(float4*)&out[(size_t)row * 64 + gl * 8 + 4] = ob;
        }
    }
}

// ---------------- launch ----------------

extern "C" void kernel_launch(void* const* d_in, const int* in_sizes, int n_in,
                              void* d_out, int out_size, void* d_ws, size_t ws_size,
                              hipStream_t stream) {
    const float* x  = (const float*)d_in[0];
    const int*   ei = (const int*)d_in[1];
    const float* W1 = (const float*)d_in[2];
    const float* b1 = (const float*)d_in[3];
    const float* W2 = (const float*)d_in[4];
    const float* b2 = (const float*)d_in[5];
    float* out = (float*)d_out;

    int N = in_sizes[0] / 256;
    int E = in_sizes[1] / 2;
    int nblk = (N + 1023) / 1024;
    int ntiles = (N + 63) / 64;

    int shift = 0;
    while ((((long)N - 1) >> shift) >= 256) shift++;
    int NB = (int)(((long)(N - 1) >> shift) + 1);

    char* ws = (char*)d_ws;
    size_t off = 0;
    auto carve = [&](size_t bytes) -> void* {
        void* p = ws + off;
        off += (bytes + 255) & ~(size_t)255;
        return p;
    };
    int*            cnt     = (int*)carve((size_t)N * 4);
    int*            row_ptr = (int*)carve((size_t)(N + 1) * 4);
    int*            partial = (int*)carve((size_t)nblk * 4);
    int*            blkoff  = (int*)carve((size_t)nblk * 4);
    int*            bcnt    = (int*)carve(256 * 4);
    int*            boff    = (int*)carve(257 * 4);
    int*            gcur    = (int*)carve((size_t)NB * 4);
    float*          dinv    = (float*)carve((size_t)N * 4);
    int2*           packed  = (int2*)carve((size_t)E * 8);
    unsigned short* W1f     = (unsigned short*)carve(256 * 256 * 2);
    unsigned short* W2f     = (unsigned short*)carve(64 * 256 * 2);
    unsigned short* h0b     = (unsigned short*)carve((size_t)N * 64 * 2);
    unsigned short* hAb     = (unsigned short*)carve((size_t)N * 64 * 2);
    unsigned short* hBb     = (unsigned short*)carve((size_t)N * 64 * 2);
    int2*           grouped = (int2*)carve((size_t)E * 8);

    size_t xb_bytes = (size_t)ntiles * 16384 * 2;
    size_t grouped_sz = ((size_t)E * 8 + 255) & ~(size_t)255;
    unsigned short* xb = nullptr;
    if (xb_bytes <= grouped_sz) {
        xb = (unsigned short*)grouped;
    } else if (off + (xb_bytes - grouped_sz) + 256 <= ws_size) {
        carve(xb_bytes - grouped_sz);
        xb = (unsigned short*)grouped;
    }

    hipMemsetAsync(bcnt, 0, 256 * 4, stream);
    hipMemsetAsync(gcur, 0, (size_t)NB * 4, stream);

    k_bcount<<<256, 256, 0, stream>>>(ei, E, shift, bcnt);
    k_boff<<<1, 256, 0, stream>>>(bcnt, boff);
    int bgrid = (int)(((long)E + CHUNK - 1) / CHUNK);
    k_bucket2<<<bgrid, 256, 0, stream>>>(ei, E, boff, gcur, grouped, shift, NB);
    k_rowcnt<<<NB, 256, 0, stream>>>(grouped, boff, cnt, dinv, shift, N);
    k_scan_part<<<nblk, 256, 0, stream>>>(cnt, partial, N);
    k_scan_off<<<1, 128, 0, stream>>>(partial, blkoff, row_ptr + N, nblk);
    k_scan_write<<<nblk, 256, 0, stream>>>(cnt, blkoff, row_ptr, N);
    k_fill2<<<NB, 256, 0, stream>>>(grouped, row_ptr, dinv, packed, shift, N);
    k_convert<<<320, 256, 0, stream>>>(W1, W2, W1f, W2f);

    if (xb) {
        long total_f4 = (long)ntiles * 64 * 64;
        int xg = (int)((total_f4 + 255) / 256);
        k_xconv<<<xg, 256, 0, stream>>>(x, xb, N, total_f4);
        k_mlp_fast<<<ntiles, 256, 0, stream>>>(xb, W1f, b1, W2f, b2, h0b, hAb, N);
    } else {
        k_mlp_slow<<<ntiles, 256, 0, stream>>>(x, W1f, b1, W2f, b2, h0b, hAb, N);
    }

    const unsigned short* hin = hAb;
    unsigned short* hout = hBb;
    for (int it = 0; it < K_ITERS; ++it) {
        int last = (it == K_ITERS - 1) ? 1 : 0;
        k_prop<<<(N + 31) / 32, 256, 0, stream>>>(hin, hout, h0b, row_ptr, packed,
                                                  dinv, N, last, out);
        const unsigned short* tmp = hin;
        hin = hout;
        hout = (unsigned short*)tmp;
    }
}